// Round 2
// baseline (95.164 us; speedup 1.0000x reference)
//
#include <hip/hip_runtime.h>
#include <hip/hip_bf16.h>

#define S_LEN 8192
#define DKD   64
#define BM    128     // queries per block (4 waves x 2 groups x 16 rows)
#define BN    64      // keys per tile
#define PAD   8
#define LDK   (DKD + PAD)   // (fallback kernel only)

#define CHUNK 256               // keys per split-K chunk (4 x 64-key tiles)
#define NC    (S_LEN / CHUNK)   // 32 chunks
#define NWORK 1056              // live (qt, cch) pairs = sum_{g=0}^{31} 2(g+1)

// ws: Ff frag-linear K/V (2MB) + l(1MB) + Opart bf16(32MB) ~= 35MB
#define WS_NEED ((size_t)2 * S_LEN * DKD * 2 + (size_t)NC * S_LEN * 4 + (size_t)NC * S_LEN * DKD * 2)

typedef __bf16 bf16x8 __attribute__((ext_vector_type(8)));
typedef float  f32x4  __attribute__((ext_vector_type(4)));
typedef unsigned short ushort8v __attribute__((ext_vector_type(8)));
typedef unsigned short ushort4v __attribute__((ext_vector_type(4)));

typedef __attribute__((address_space(3))) unsigned int lds_uint;
typedef const __attribute__((address_space(1))) unsigned int glb_uint;

__device__ __forceinline__ unsigned short f2bf(float f) {   // RNE
  union { float f; unsigned u; } v; v.f = f;
  unsigned u = v.u;
  return (unsigned short)((u + 0x7fffu + ((u >> 16) & 1u)) >> 16);
}
__device__ __forceinline__ float bf2f(unsigned short s) {
  union { unsigned u; float f; } v; v.u = ((unsigned)s) << 16;
  return v.f;
}
__device__ __forceinline__ unsigned pk2(float a, float b) {  // two f32 -> bf16x2
  union { float f; unsigned u; } x, y; x.f = a; y.f = b;
  return ((x.u + 0x8000u) >> 16) | ((y.u + 0x8000u) & 0xffff0000u);
}
__device__ __forceinline__ bf16x8 q_frag8(const float* p, float sc) {
  float4 u = *(const float4*)p;
  float4 w = *(const float4*)(p + 4);
  union { ushort8v s; bf16x8 b; } r;
  r.s[0] = f2bf(u.x * sc); r.s[1] = f2bf(u.y * sc);
  r.s[2] = f2bf(u.z * sc); r.s[3] = f2bf(u.w * sc);
  r.s[4] = f2bf(w.x * sc); r.s[5] = f2bf(w.y * sc);
  r.s[6] = f2bf(w.z * sc); r.s[7] = f2bf(w.w * sc);
  return r.b;
}

// ---------------------------------------------------------------------------
// Precompute fragment-linear K/V: Ff[tile][f][lane] as 16B chunks (verified
// R8-R10).  f in [0,8): K A-frag (t=f>>1, c=f&1):
//   K[tile*64+16t+col][c*32+quad*8+j]
// f in [8,16): V B-frag (dt,c): V[tile*64+s(kk)][16dt+col], kk=c*32+quad*8+j,
//   s(kk) = ((kk&7)>>2 + 2*(kk>>5))*16 + ((kk>>3)&3)*4 + (kk&3)
// ---------------------------------------------------------------------------
__global__ __launch_bounds__(256) void precompute(const float* __restrict__ k,
                                                  const float* __restrict__ v,
                                                  unsigned short* __restrict__ Ff) {
  __shared__ unsigned short Ls[64][72];
  const int b = blockIdx.x, tid = threadIdx.x;
  unsigned short* tb = Ff + ((size_t)b << 13);   // 8192 shorts per tile

#pragma unroll
  for (int j = 0; j < 4; ++j) {
    int vi = tid + j * 256;
    int row = vi >> 4, c4 = vi & 15;
    float4 x = *(const float4*)(v + ((size_t)(b * 64 + row)) * DKD + c4 * 4);
    Ls[row][c4 * 4 + 0] = f2bf(x.x);
    Ls[row][c4 * 4 + 1] = f2bf(x.y);
    Ls[row][c4 * 4 + 2] = f2bf(x.z);
    Ls[row][c4 * 4 + 3] = f2bf(x.w);
  }

#pragma unroll
  for (int j = 0; j < 2; ++j) {
    int idx = tid + j * 256;
    int f = idx >> 6, lane = idx & 63;
    int col = lane & 15, quad = lane >> 4;
    int t = f >> 1, c = f & 1;
    const float* src = k + ((size_t)(b * 64 + 16 * t + col)) * DKD + c * 32 + quad * 8;
    union { ushort8v s; bf16x8 bb; } r;
    r.bb = q_frag8(src, 1.0f);
    *(ushort8v*)(tb + (size_t)(f * 64 + lane) * 8) = r.s;
  }
  __syncthreads();

#pragma unroll
  for (int j = 0; j < 2; ++j) {
    int idx = tid + j * 256;
    int f8 = idx >> 6, lane = idx & 63;
    int col = lane & 15, quad = lane >> 4;
    int dt = f8 >> 1, c = f8 & 1;
    int d = 16 * dt + col;
    ushort8v o;
#pragma unroll
    for (int j2 = 0; j2 < 8; ++j2) {
      int kk = c * 32 + quad * 8 + j2;
      int s = (((kk & 7) >> 2) + 2 * (kk >> 5)) * 16 + (((kk >> 3) & 3) << 2) + (kk & 3);
      o[j2] = Ls[s][d];
    }
    *(ushort8v*)(tb + (size_t)((8 + f8) * 64 + lane) * 8) = o;
  }
}

// async frag-linear tile stage: 16 KB, direct global->LDS, lane*16B pattern.
// Exactly 4 global_load_lds per WAVE per call (vmcnt accounting relies on it).
__device__ __forceinline__ void stage_tile(const unsigned short* tb,
                                           unsigned short* dst,
                                           int wave) {
#pragma unroll
  for (int p = 0; p < 4; ++p) {
    const int seg = p * 4 + wave;      // 16 segs of 64 lanes x 16B
    __builtin_amdgcn_global_load_lds(
        (glb_uint*)(tb + ((size_t)seg << 9) + (size_t)(threadIdx.x & 63) * 8),
        (lds_uint*)(dst + ((size_t)seg << 9)),
        16, 0, 0);
  }
}

// ---------------------------------------------------------------------------
// Phase 1: BM=128, CHUNK=256 (max 4 key-tiles per block -> short chains,
// 1056 blocks for load balance).  3-buffer 2-deep prefetch with counted
// s_waitcnt vmcnt(4): staged tiles get ~2 compute phases to land; the main
// loop never drains vmcnt to 0 (T3/T4).  All fragment layouts identical to
// the verified version; conflict-free contiguous ds_read_b128, S^T trick
// keeps P in registers.
// ---------------------------------------------------------------------------
__global__ __launch_bounds__(256, 2) void attn_partial(const float* __restrict__ qg,
                                                       const unsigned short* __restrict__ Ff,
                                                       unsigned short* __restrict__ Opart,
                                                       float* __restrict__ l_ws) {
  // decode reversed work index -> (qt, cch): qt in 128-row units; group
  // g = qt>>1 (2 qt's per group, g+1 chunks each); blocks before group g:
  // g(g+1).
  const int wr = (NWORK - 1) - blockIdx.x;
  int g = (int)((sqrtf((float)(4 * wr) + 1.0f) - 1.0f) * 0.5f);
  while ((g + 1) * (g + 2) <= wr) ++g;
  while (g * (g + 1) > wr) --g;
  const int r0  = wr - g * (g + 1);
  const int qq  = r0 / (g + 1);
  const int qt  = 2 * g + qq;
  const int cch = r0 - qq * (g + 1);

  const int q0 = qt * BM, chunk0 = cch * CHUNK;
  const int n_kt = min(CHUNK / BN, 2 * (qt - 2 * cch) + 2);
  const int tile0 = cch * 4;

  __shared__ __align__(16) unsigned short Buf[3][8192];   // 3 x 16KB tiles

  const int tid = threadIdx.x, wave = tid >> 6, lane = tid & 63;
  const int col = lane & 15, quad = lane >> 4;

  // Q B-fragments for both groups (scale 1/64 folded in); q = col
  const int qidxA = q0 + wave * 16 + col;
  const int qidxB = qidxA + 64;
  const float* qpA = qg + (size_t)qidxA * DKD;
  const float* qpB = qg + (size_t)qidxB * DKD;
  bf16x8 a0 = q_frag8(qpA + quad * 8, 1.0f / 64.0f);
  bf16x8 a1 = q_frag8(qpA + 32 + quad * 8, 1.0f / 64.0f);
  bf16x8 c0 = q_frag8(qpB + quad * 8, 1.0f / 64.0f);
  bf16x8 c1 = q_frag8(qpB + 32 + quad * 8, 1.0f / 64.0f);

  float lsumA = 0.0f, lsumB = 0.0f;
  f32x4 OfA[4], OfB[4];
#pragma unroll
  for (int i = 0; i < 4; ++i) {
    OfA[i] = f32x4{0.0f, 0.0f, 0.0f, 0.0f};
    OfB[i] = f32x4{0.0f, 0.0f, 0.0f, 0.0f};
  }

  // Drain Q loads so in-loop vmcnt counts ONLY stage loads (4/wave/stage).
  asm volatile("s_waitcnt vmcnt(0)" ::: "memory");

  stage_tile(Ff + ((size_t)tile0 << 13), &Buf[0][0], wave);
  if (n_kt > 1)
    stage_tile(Ff + ((size_t)(tile0 + 1) << 13), &Buf[1][0], wave);

  // wait: tile 0 complete (leave tile 1's 4 loads in flight)
  if (n_kt > 1) asm volatile("s_waitcnt vmcnt(4)" ::: "memory");
  else          asm volatile("s_waitcnt vmcnt(0)" ::: "memory");
  __builtin_amdgcn_s_barrier();
  __builtin_amdgcn_sched_barrier(0);

  for (int it = 0; it < n_kt; ++it) {
    if (it + 2 < n_kt)
      stage_tile(Ff + ((size_t)(tile0 + it + 2) << 13), &Buf[(it + 2) % 3][0], wave);

    const unsigned short* B = &Buf[it % 3][0];
    const int k0 = chunk0 + it * BN;

    // K fragments (contiguous lane*16B -> conflict-free b128), shared by
    // both query groups
    bf16x8 kf[8];
#pragma unroll
    for (int f = 0; f < 8; ++f)
      kf[f] = *(const bf16x8*)(B + (size_t)((f << 6) + lane) * 8);

    // S^T = K Q^T : lane holds S^T[key = t*16 + quad*4 + r][q = col]
    f32x4 SA[4], SB[4];
#pragma unroll
    for (int t = 0; t < 4; ++t) {
      f32x4 acc = f32x4{0.0f, 0.0f, 0.0f, 0.0f};
      acc = __builtin_amdgcn_mfma_f32_16x16x32_bf16(kf[2 * t], a0, acc, 0, 0, 0);
      acc = __builtin_amdgcn_mfma_f32_16x16x32_bf16(kf[2 * t + 1], a1, acc, 0, 0, 0);
      SA[t] = acc;
    }
#pragma unroll
    for (int t = 0; t < 4; ++t) {
      f32x4 acc = f32x4{0.0f, 0.0f, 0.0f, 0.0f};
      acc = __builtin_amdgcn_mfma_f32_16x16x32_bf16(kf[2 * t], c0, acc, 0, 0, 0);
      acc = __builtin_amdgcn_mfma_f32_16x16x32_bf16(kf[2 * t + 1], c1, acc, 0, 0, 0);
      SB[t] = acc;
    }

    // V fragments in flight during exp/pack (shared by both groups)
    bf16x8 vf[8];
#pragma unroll
    for (int f = 0; f < 8; ++f)
      vf[f] = *(const bf16x8*)(B + (size_t)(((8 + f) << 6) + lane) * 8);

    // causal mask + exact no-max softmax: p = (key <= q) ? exp(s) : 0
#pragma unroll
    for (int t = 0; t < 4; ++t) {
      int kb = k0 + t * 16 + quad * 4;
#pragma unroll
      for (int r = 0; r < 4; ++r) {
        float pA = __expf(SA[t][r]);
        pA = (kb + r <= qidxA) ? pA : 0.0f;
        SA[t][r] = pA;
        lsumA += pA;
        float pB = __expf(SB[t][r]);
        pB = (kb + r <= qidxB) ? pB : 0.0f;
        SB[t][r] = pB;
        lsumB += pB;
      }
    }

    // pack P^T -> A-fragments (k-order matches Ff's V permutation)
    union { unsigned u[4]; bf16x8 b; } pa0, pa1, pb0, pb1;
    pa0.u[0] = pk2(SA[0][0], SA[0][1]); pa0.u[1] = pk2(SA[0][2], SA[0][3]);
    pa0.u[2] = pk2(SA[1][0], SA[1][1]); pa0.u[3] = pk2(SA[1][2], SA[1][3]);
    pa1.u[0] = pk2(SA[2][0], SA[2][1]); pa1.u[1] = pk2(SA[2][2], SA[2][3]);
    pa1.u[2] = pk2(SA[3][0], SA[3][1]); pa1.u[3] = pk2(SA[3][2], SA[3][3]);
    pb0.u[0] = pk2(SB[0][0], SB[0][1]); pb0.u[1] = pk2(SB[0][2], SB[0][3]);
    pb0.u[2] = pk2(SB[1][0], SB[1][1]); pb0.u[3] = pk2(SB[1][2], SB[1][3]);
    pb1.u[0] = pk2(SB[2][0], SB[2][1]); pb1.u[1] = pk2(SB[2][2], SB[2][3]);
    pb1.u[2] = pk2(SB[3][0], SB[3][1]); pb1.u[3] = pk2(SB[3][2], SB[3][3]);

    // O += P V  (V fragments reused across both groups)
#pragma unroll
    for (int dt = 0; dt < 4; ++dt) {
      OfA[dt] = __builtin_amdgcn_mfma_f32_16x16x32_bf16(pa0.b, vf[2 * dt], OfA[dt], 0, 0, 0);
      OfA[dt] = __builtin_amdgcn_mfma_f32_16x16x32_bf16(pa1.b, vf[2 * dt + 1], OfA[dt], 0, 0, 0);
    }
#pragma unroll
    for (int dt = 0; dt < 4; ++dt) {
      OfB[dt] = __builtin_amdgcn_mfma_f32_16x16x32_bf16(pb0.b, vf[2 * dt], OfB[dt], 0, 0, 0);
      OfB[dt] = __builtin_amdgcn_mfma_f32_16x16x32_bf16(pb1.b, vf[2 * dt + 1], OfB[dt], 0, 0, 0);
    }

    // barrier: next iter overwrites buf[it%3] via stage(it+3) and reads
    // buf[(it+1)%3].  Counted wait: only require stage(it+1) landed; leave
    // stage(it+2)'s 4 loads in flight.  lgkmcnt(0): this wave's ds_reads of
    // buf[it%3] are complete before the overwrite.  Last iter: no reuse ->
    // no barrier.
    if (it + 1 < n_kt) {
      if (it + 2 < n_kt) asm volatile("s_waitcnt vmcnt(4) lgkmcnt(0)" ::: "memory");
      else               asm volatile("s_waitcnt vmcnt(0) lgkmcnt(0)" ::: "memory");
      __builtin_amdgcn_s_barrier();
      __builtin_amdgcn_sched_barrier(0);
    }
  }

  // l: sum the 4 quad-partials per q (lane bits 4,5)
  lsumA += __shfl_xor(lsumA, 16);
  lsumA += __shfl_xor(lsumA, 32);
  lsumB += __shfl_xor(lsumB, 16);
  lsumB += __shfl_xor(lsumB, 32);
  if (lane < 16) {
    l_ws[cch * S_LEN + q0 + wave * 16 + lane] = lsumA;
    l_ws[cch * S_LEN + q0 + 64 + wave * 16 + lane] = lsumB;
  }

  // store k-permuted bf16 partials (sd = col*4 + dt; merge unpermutes)
#pragma unroll
  for (int r = 0; r < 4; ++r) {
    int rowgA = q0 + wave * 16 + quad * 4 + r;
    uint2 oA;
    oA.x = pk2(OfA[0][r], OfA[1][r]);
    oA.y = pk2(OfA[2][r], OfA[3][r]);
    *(uint2*)(Opart + ((size_t)cch * S_LEN + rowgA) * DKD + col * 4) = oA;
    uint2 oB;
    oB.x = pk2(OfB[0][r], OfB[1][r]);
    oB.y = pk2(OfB[2][r], OfB[3][r]);
    *(uint2*)(Opart + ((size_t)cch * S_LEN + rowgA + 64) * DKD + col * 4) = oB;
  }
}

// ---------------------------------------------------------------------------
// Phase 2: sum partials over live chunks, unpermute sd -> d, normalize.
// ---------------------------------------------------------------------------
__global__ __launch_bounds__(256) void attn_merge(const unsigned short* __restrict__ Opart,
                                                  const float* __restrict__ l_ws,
                                                  float* __restrict__ out) {
  int idx = blockIdx.x * 256 + threadIdx.x;   // S*8 threads
  int row = idx >> 3, m = idx & 7;
  int nc = (row >> 8) + 1;   // chunks with chunk_start <= row (CHUNK=256)

  float acc[8] = {0, 0, 0, 0, 0, 0, 0, 0};
  float L = 0.0f;
  for (int c = 0; c < nc; ++c) {
    L += l_ws[c * S_LEN + row];
    ushort8v o = *(const ushort8v*)(Opart + ((size_t)c * S_LEN + row) * DKD + m * 8);
#pragma unroll
    for (int j = 0; j < 8; ++j) acc[j] += bf2f(o[j]);
  }
  float inv = 1.0f / L;
  // sd = 8m + j ; d = 16*(j&3) + 2m + (j>>2)
#pragma unroll
  for (int j0 = 0; j0 < 4; ++j0) {
    float2 w2 = { acc[j0] * inv, acc[j0 + 4] * inv };
    *(float2*)(out + (size_t)row * DKD + 16 * j0 + 2 * m) = w2;
  }
}

// ---------------------------------------------------------------------------
// Fallback (ws too small): single-pass flash kernel, fp32 inputs.
// ---------------------------------------------------------------------------
__global__ __launch_bounds__(128) void attn_fwd(const float* __restrict__ qg,
                                                const float* __restrict__ kg,
                                                const float* __restrict__ vg,
                                                float* __restrict__ out) {
  __shared__ __align__(16) unsigned short Qs[32][LDK];
  __shared__ __align__(16) unsigned short Ksh[BN][LDK];
  __shared__ __align__(16) unsigned short Vt[DKD][LDK];
  __shared__ __align__(16) unsigned short Ps[2][16][LDK];

  const int tid = threadIdx.x, wave = tid >> 6, lane = tid & 63;
  const int col = lane & 15, quad = lane >> 4;
  const int q0 = blockIdx.x * 32;

#pragma unroll
  for (int r = 0; r < 4; ++r) {
    int vi = tid + r * 128;
    int row = vi >> 4, c4 = vi & 15;
    if (row < 32) {
      float4 val = *(const float4*)(qg + (size_t)(q0 + row) * DKD + c4 * 4);
      Qs[row][c4 * 4 + 0] = f2bf(val.x);
      Qs[row][c4 * 4 + 1] = f2bf(val.y);
      Qs[row][c4 * 4 + 2] = f2bf(val.z);
      Qs[row][c4 * 4 + 3] = f2bf(val.w);
    }
  }

  float m_run[4], l_run[4];
  f32x4 Of[4];
#pragma unroll
  for (int i = 0; i < 4; ++i) {
    m_run[i] = -1e30f; l_run[i] = 0.0f;
    Of[i] = f32x4{0.0f, 0.0f, 0.0f, 0.0f};
  }

  const int n_tiles = (q0 + 31) / BN + 1;
  for (int it = 0; it < n_tiles; ++it) {
    __syncthreads();
    const int k0 = it * BN;
#pragma unroll
    for (int r = 0; r < 8; ++r) {
      int vi = tid + r * 128;
      int row = vi >> 4, c4 = vi & 15;
      float4 kv = *(const float4*)(kg + (size_t)(k0 + row) * DKD + c4 * 4);
      Ksh[row][c4 * 4 + 0] = f2bf(kv.x);
      Ksh[row][c4 * 4 + 1] = f2bf(kv.y);
      Ksh[row][c4 * 4 + 2] = f2bf(kv.z);
      Ksh[row][c4 * 4 + 3] = f2bf(kv.w);
      float4 vv = *(const float4*)(vg + (size_t)(k0 + row) * DKD + c4 * 4);
      Vt[c4 * 4 + 0][row] = f2bf(vv.x);
      Vt[c4 * 4 + 1][row] = f2bf(vv.y);
      Vt[c4 * 4 + 2][row] = f2bf(vv.z);
      Vt[c4 * 4 + 3][row] = f2bf(vv.w);
    }
    __syncthreads();

    f32x4 Sf[4];
    const unsigned short* qrow = &Qs[wave * 16 + col][0];
#pragma unroll
    for (int t = 0; t < 4; ++t) {
      f32x4 acc = f32x4{0.0f, 0.0f, 0.0f, 0.0f};
#pragma unroll
      for (int c = 0; c < 2; ++c) {
        bf16x8 a = *(const bf16x8*)(qrow + c * 32 + quad * 8);
        bf16x8 b = *(const bf16x8*)(&Ksh[t * 16 + col][c * 32 + quad * 8]);
        acc = __builtin_amdgcn_mfma_f32_16x16x32_bf16(a, b, acc, 0, 0, 0);
      }
      Sf[t] = acc;
    }

    const float scale = 1.0f / 64.0f;
    float rmax[4] = {-1e30f, -1e30f, -1e30f, -1e30f};
#pragma unroll
    for (int t = 0; t < 4; ++t) {
      int kidx = k0 + t * 16 + col;
#pragma unroll
      for (int r = 0; r < 4; ++r) {
        int qidx = q0 + wave * 16 + quad * 4 + r;
        float s = Sf[t][r] * scale;
        s = (kidx <= qidx) ? s : -1e30f;
        Sf[t][r] = s;
        rmax[r] = fmaxf(rmax[r], s);
      }
    }
#pragma unroll
    for (int off = 1; off <= 8; off <<= 1)
#pragma unroll
      for (int r = 0; r < 4; ++r)
        rmax[r] = fmaxf(rmax[r], __shfl_xor(rmax[r], off));

    float alpha[4], rsum[4];
#pragma unroll
    for (int r = 0; r < 4; ++r) {
      float mn = fmaxf(m_run[r], rmax[r]);
      alpha[r] = __expf(m_run[r] - mn);
      m_run[r] = mn;
      rsum[r] = 0.0f;
    }
#pragma unroll
    for (int t = 0; t < 4; ++t)
#pragma unroll
      for (int r = 0; r < 4; ++r) {
        float p = __expf(Sf[t][r] - m_run[r]);
        Sf[t][r] = p;
        rsum[r] += p;
      }
#pragma unroll
    for (int off = 1; off <= 8; off <<= 1)
#pragma unroll
      for (int r = 0; r < 4; ++r)
        rsum[r] += __shfl_xor(rsum[r], off);
#pragma unroll
    for (int r = 0; r < 4; ++r)
      l_run[r] = l_run[r] * alpha[r] + rsum[r];
#pragma unroll
    for (int dt = 0; dt < 4; ++dt)
#pragma unroll
      for (int r = 0; r < 4; ++r)
        Of[dt][r] *= alpha[r];

#pragma unroll
    for (int t = 0; t < 4; ++t)
#pragma unroll
      for (int r = 0; r < 4; ++r)
        Ps[wave][quad * 4 + r][t * 16 + col] = f2bf(Sf[t][r]);
    __syncthreads();

    const unsigned short* prow = &Ps[wave][col][0];
#pragma unroll
    for (int dt = 0; dt < 4; ++dt) {
#pragma unroll
      for (int c = 0; c < 2; ++c) {
        bf16x8 a = *(const bf16x8*)(prow + c * 32 + quad * 8);
        bf16x8 b = *(const bf16x8*)(&Vt[dt * 16 + col][c * 32 + quad * 8]);
        Of[dt] = __builtin_amdgcn_mfma_f32_16x16x32_bf16(a, b, Of[dt], 0, 0, 0);
      }
    }
  }

#pragma unroll
  for (int r = 0; r < 4; ++r) {
    float inv = 1.0f / l_run[r];
    int qrow_g = q0 + wave * 16 + quad * 4 + r;
#pragma unroll
    for (int dt = 0; dt < 4; ++dt)
      out[(size_t)qrow_g * DKD + dt * 16 + col] = Of[dt][r] * inv;
  }
}

extern "C" void kernel_launch(void* const* d_in, const int* in_sizes, int n_in,
                              void* d_out, int out_size, void* d_ws, size_t ws_size,
                              hipStream_t stream) {
  const float* q = (const float*)d_in[0];
  const float* k = (const float*)d_in[1];
  const float* v = (const float*)d_in[2];
  float* out = (float*)d_out;

  if (ws_size >= WS_NEED) {
    unsigned short* Ff    = (unsigned short*)d_ws;
    float* l_ws           = (float*)(Ff + (size_t)2 * S_LEN * DKD);
    unsigned short* Opart = (unsigned short*)(l_ws + (size_t)NC * S_LEN);

    hipLaunchKernelGGL(precompute, dim3(S_LEN / 64), dim3(256), 0, stream, k, v, Ff);
    hipLaunchKernelGGL(attn_partial, dim3(NWORK), dim3(256), 0, stream,
                       q, Ff, Opart, l_ws);
    hipLaunchKernelGGL(attn_merge, dim3(S_LEN * 8 / 256), dim3(256), 0, stream,
                       Opart, l_ws, out);
  } else {
    hipLaunchKernelGGL(attn_fwd, dim3(S_LEN / 32), dim3(128), 0, stream, q, k, v, out);
  }
}

// Round 3
// 89.446 us; speedup vs baseline: 1.0639x; 1.0639x over previous
//
#include <hip/hip_runtime.h>
#include <hip/hip_bf16.h>

#define S_LEN 8192
#define DKD   64
#define BM    128     // queries per block (4 waves x 2 groups x 16 rows)
#define BN    64      // keys per tile
#define PAD   8
#define LDK   (DKD + PAD)   // (fallback kernel only)

#define CHUNK 512               // keys per split-K chunk
#define NC    (S_LEN / CHUNK)   // 16 chunks
#define NWORK 544               // live (qt, cch) pairs = 2*16*17 (qt in 128-row units)

// ws: Ff frag-linear K/V (2MB) + l(512KB) + Opart bf16(16MB) ~= 18.5MB
#define WS_NEED ((size_t)2 * S_LEN * DKD * 2 + (size_t)NC * S_LEN * 4 + (size_t)NC * S_LEN * DKD * 2)

typedef __bf16 bf16x8 __attribute__((ext_vector_type(8)));
typedef float  f32x4  __attribute__((ext_vector_type(4)));
typedef unsigned short ushort8v __attribute__((ext_vector_type(8)));
typedef unsigned short ushort4v __attribute__((ext_vector_type(4)));

__device__ __forceinline__ unsigned short f2bf(float f) {   // RNE
  union { float f; unsigned u; } v; v.f = f;
  unsigned u = v.u;
  return (unsigned short)((u + 0x7fffu + ((u >> 16) & 1u)) >> 16);
}
__device__ __forceinline__ float bf2f(unsigned short s) {
  union { unsigned u; float f; } v; v.u = ((unsigned)s) << 16;
  return v.f;
}
__device__ __forceinline__ unsigned pk2(float a, float b) {  // two f32 -> bf16x2
  union { float f; unsigned u; } x, y; x.f = a; y.f = b;
  return ((x.u + 0x8000u) >> 16) | ((y.u + 0x8000u) & 0xffff0000u);
}
__device__ __forceinline__ bf16x8 q_frag8(const float* p, float sc) {
  float4 u = *(const float4*)p;
  float4 w = *(const float4*)(p + 4);
  union { ushort8v s; bf16x8 b; } r;
  r.s[0] = f2bf(u.x * sc); r.s[1] = f2bf(u.y * sc);
  r.s[2] = f2bf(u.z * sc); r.s[3] = f2bf(u.w * sc);
  r.s[4] = f2bf(w.x * sc); r.s[5] = f2bf(w.y * sc);
  r.s[6] = f2bf(w.z * sc); r.s[7] = f2bf(w.w * sc);
  return r.b;
}

// ---------------------------------------------------------------------------
// Precompute fragment-linear K/V: Ff[tile][f][lane] as 16B chunks (verified
// R8-R10).  f in [0,8): K A-frag (t=f>>1, c=f&1):
//   K[tile*64+16t+col][c*32+quad*8+j]
// f in [8,16): V B-frag (dt,c): V[tile*64+s(kk)][16dt+col], kk=c*32+quad*8+j,
//   s(kk) = ((kk&7)>>2 + 2*(kk>>5))*16 + ((kk>>3)&3)*4 + (kk&3)
// ---------------------------------------------------------------------------
__global__ __launch_bounds__(256) void precompute(const float* __restrict__ k,
                                                  const float* __restrict__ v,
                                                  unsigned short* __restrict__ Ff) {
  __shared__ unsigned short Ls[64][72];
  const int b = blockIdx.x, tid = threadIdx.x;
  unsigned short* tb = Ff + ((size_t)b << 13);   // 8192 shorts per tile

#pragma unroll
  for (int j = 0; j < 4; ++j) {
    int vi = tid + j * 256;
    int row = vi >> 4, c4 = vi & 15;
    float4 x = *(const float4*)(v + ((size_t)(b * 64 + row)) * DKD + c4 * 4);
    Ls[row][c4 * 4 + 0] = f2bf(x.x);
    Ls[row][c4 * 4 + 1] = f2bf(x.y);
    Ls[row][c4 * 4 + 2] = f2bf(x.z);
    Ls[row][c4 * 4 + 3] = f2bf(x.w);
  }

#pragma unroll
  for (int j = 0; j < 2; ++j) {
    int idx = tid + j * 256;
    int f = idx >> 6, lane = idx & 63;
    int col = lane & 15, quad = lane >> 4;
    int t = f >> 1, c = f & 1;
    const float* src = k + ((size_t)(b * 64 + 16 * t + col)) * DKD + c * 32 + quad * 8;
    union { ushort8v s; bf16x8 bb; } r;
    r.bb = q_frag8(src, 1.0f);
    *(ushort8v*)(tb + (size_t)(f * 64 + lane) * 8) = r.s;
  }
  __syncthreads();

#pragma unroll
  for (int j = 0; j < 2; ++j) {
    int idx = tid + j * 256;
    int f8 = idx >> 6, lane = idx & 63;
    int col = lane & 15, quad = lane >> 4;
    int dt = f8 >> 1, c = f8 & 1;
    int d = 16 * dt + col;
    ushort8v o;
#pragma unroll
    for (int j2 = 0; j2 < 8; ++j2) {
      int kk = c * 32 + quad * 8 + j2;
      int s = (((kk & 7) >> 2) + 2 * (kk >> 5)) * 16 + (((kk >> 3) & 3) << 2) + (kk & 3);
      o[j2] = Ls[s][d];
    }
    *(ushort8v*)(tb + (size_t)((8 + f8) * 64 + lane) * 8) = o;
  }
}

// ---------------------------------------------------------------------------
// Phase 1: BM=128, CHUNK=512 (R1 geometry, proven) but NO LDS, NO BARRIERS:
// K/V fragments load directly global->register from the frag-linear Ff
// (16B/lane coalesced, L2-resident: Ff is 2MB < 4MB per-XCD L2).  Waves
// free-run — no lockstep, no vmcnt drains; latency hidden by 16 parallel
// outstanding loads/iter + 8 waves/CU.  S^T trick keeps P in registers.
// ---------------------------------------------------------------------------
__global__ __launch_bounds__(256, 2) void attn_partial(const float* __restrict__ qg,
                                                       const unsigned short* __restrict__ Ff,
                                                       unsigned short* __restrict__ Opart,
                                                       float* __restrict__ l_ws) {
  // decode reversed work index -> (qt, cch): qt in 128-row units has
  // qt/4 + 1 chunks; group g = qt>>2 (4 qt's per group); blocks before
  // group g: 2g(g+1).
  const int wr = (NWORK - 1) - blockIdx.x;
  int g = (int)((sqrtf((float)(2 * wr) + 1.0f) - 1.0f) * 0.5f);
  while (2 * (g + 1) * (g + 2) <= wr) ++g;
  while (2 * g * (g + 1) > wr) --g;
  const int r0  = wr - 2 * g * (g + 1);
  const int qq  = r0 / (g + 1);
  const int qt  = 4 * g + qq;
  const int cch = r0 - qq * (g + 1);

  const int q0 = qt * BM, chunk0 = cch * CHUNK;
  const int n_kt = min(CHUNK / BN, 2 * (qt - 4 * cch) + 2);
  const int tile0 = cch * 8;

  const int tid = threadIdx.x, wave = tid >> 6, lane = tid & 63;
  const int col = lane & 15, quad = lane >> 4;

  // Q B-fragments for both groups (scale 1/64 folded in); q = col
  const int qidxA = q0 + wave * 16 + col;
  const int qidxB = qidxA + 64;
  const float* qpA = qg + (size_t)qidxA * DKD;
  const float* qpB = qg + (size_t)qidxB * DKD;
  bf16x8 a0 = q_frag8(qpA + quad * 8, 1.0f / 64.0f);
  bf16x8 a1 = q_frag8(qpA + 32 + quad * 8, 1.0f / 64.0f);
  bf16x8 c0 = q_frag8(qpB + quad * 8, 1.0f / 64.0f);
  bf16x8 c1 = q_frag8(qpB + 32 + quad * 8, 1.0f / 64.0f);

  float lsumA = 0.0f, lsumB = 0.0f;
  f32x4 OfA[4], OfB[4];
#pragma unroll
  for (int i = 0; i < 4; ++i) {
    OfA[i] = f32x4{0.0f, 0.0f, 0.0f, 0.0f};
    OfB[i] = f32x4{0.0f, 0.0f, 0.0f, 0.0f};
  }

  for (int it = 0; it < n_kt; ++it) {
    const unsigned short* tb = Ff + ((size_t)(tile0 + it) << 13);
    const int k0 = chunk0 + it * BN;

    // K and V fragments straight from global (L2-hit, 16B/lane coalesced).
    // Issue all 16 loads up front for max memory-level parallelism.
    bf16x8 kf[8], vf[8];
#pragma unroll
    for (int f = 0; f < 8; ++f)
      kf[f] = *(const bf16x8*)(tb + (size_t)((f << 6) + lane) * 8);
#pragma unroll
    for (int f = 0; f < 8; ++f)
      vf[f] = *(const bf16x8*)(tb + (size_t)(((8 + f) << 6) + lane) * 8);

    // S^T = K Q^T : lane holds S^T[key = t*16 + quad*4 + r][q = col]
    f32x4 SA[4], SB[4];
#pragma unroll
    for (int t = 0; t < 4; ++t) {
      f32x4 acc = f32x4{0.0f, 0.0f, 0.0f, 0.0f};
      acc = __builtin_amdgcn_mfma_f32_16x16x32_bf16(kf[2 * t], a0, acc, 0, 0, 0);
      acc = __builtin_amdgcn_mfma_f32_16x16x32_bf16(kf[2 * t + 1], a1, acc, 0, 0, 0);
      SA[t] = acc;
    }
#pragma unroll
    for (int t = 0; t < 4; ++t) {
      f32x4 acc = f32x4{0.0f, 0.0f, 0.0f, 0.0f};
      acc = __builtin_amdgcn_mfma_f32_16x16x32_bf16(kf[2 * t], c0, acc, 0, 0, 0);
      acc = __builtin_amdgcn_mfma_f32_16x16x32_bf16(kf[2 * t + 1], c1, acc, 0, 0, 0);
      SB[t] = acc;
    }

    // causal mask + exact no-max softmax: p = (key <= q) ? exp(s) : 0
#pragma unroll
    for (int t = 0; t < 4; ++t) {
      int kb = k0 + t * 16 + quad * 4;
#pragma unroll
      for (int r = 0; r < 4; ++r) {
        float pA = __expf(SA[t][r]);
        pA = (kb + r <= qidxA) ? pA : 0.0f;
        SA[t][r] = pA;
        lsumA += pA;
        float pB = __expf(SB[t][r]);
        pB = (kb + r <= qidxB) ? pB : 0.0f;
        SB[t][r] = pB;
        lsumB += pB;
      }
    }

    // pack P^T -> A-fragments (k-order matches Ff's V permutation)
    union { unsigned u[4]; bf16x8 b; } pa0, pa1, pb0, pb1;
    pa0.u[0] = pk2(SA[0][0], SA[0][1]); pa0.u[1] = pk2(SA[0][2], SA[0][3]);
    pa0.u[2] = pk2(SA[1][0], SA[1][1]); pa0.u[3] = pk2(SA[1][2], SA[1][3]);
    pa1.u[0] = pk2(SA[2][0], SA[2][1]); pa1.u[1] = pk2(SA[2][2], SA[2][3]);
    pa1.u[2] = pk2(SA[3][0], SA[3][1]); pa1.u[3] = pk2(SA[3][2], SA[3][3]);
    pb0.u[0] = pk2(SB[0][0], SB[0][1]); pb0.u[1] = pk2(SB[0][2], SB[0][3]);
    pb0.u[2] = pk2(SB[1][0], SB[1][1]); pb0.u[3] = pk2(SB[1][2], SB[1][3]);
    pb1.u[0] = pk2(SB[2][0], SB[2][1]); pb1.u[1] = pk2(SB[2][2], SB[2][3]);
    pb1.u[2] = pk2(SB[3][0], SB[3][1]); pb1.u[3] = pk2(SB[3][2], SB[3][3]);

    // O += P V  (V fragments reused across both groups)
#pragma unroll
    for (int dt = 0; dt < 4; ++dt) {
      OfA[dt] = __builtin_amdgcn_mfma_f32_16x16x32_bf16(pa0.b, vf[2 * dt], OfA[dt], 0, 0, 0);
      OfA[dt] = __builtin_amdgcn_mfma_f32_16x16x32_bf16(pa1.b, vf[2 * dt + 1], OfA[dt], 0, 0, 0);
    }
#pragma unroll
    for (int dt = 0; dt < 4; ++dt) {
      OfB[dt] = __builtin_amdgcn_mfma_f32_16x16x32_bf16(pb0.b, vf[2 * dt], OfB[dt], 0, 0, 0);
      OfB[dt] = __builtin_amdgcn_mfma_f32_16x16x32_bf16(pb1.b, vf[2 * dt + 1], OfB[dt], 0, 0, 0);
    }
  }

  // l: sum the 4 quad-partials per q (lane bits 4,5)
  lsumA += __shfl_xor(lsumA, 16);
  lsumA += __shfl_xor(lsumA, 32);
  lsumB += __shfl_xor(lsumB, 16);
  lsumB += __shfl_xor(lsumB, 32);
  if (lane < 16) {
    l_ws[cch * S_LEN + q0 + wave * 16 + lane] = lsumA;
    l_ws[cch * S_LEN + q0 + 64 + wave * 16 + lane] = lsumB;
  }

  // store k-permuted bf16 partials (sd = col*4 + dt; merge unpermutes)
#pragma unroll
  for (int r = 0; r < 4; ++r) {
    int rowgA = q0 + wave * 16 + quad * 4 + r;
    uint2 oA;
    oA.x = pk2(OfA[0][r], OfA[1][r]);
    oA.y = pk2(OfA[2][r], OfA[3][r]);
    *(uint2*)(Opart + ((size_t)cch * S_LEN + rowgA) * DKD + col * 4) = oA;
    uint2 oB;
    oB.x = pk2(OfB[0][r], OfB[1][r]);
    oB.y = pk2(OfB[2][r], OfB[3][r]);
    *(uint2*)(Opart + ((size_t)cch * S_LEN + rowgA + 64) * DKD + col * 4) = oB;
  }
}

// ---------------------------------------------------------------------------
// Phase 2: sum partials over live chunks, unpermute sd -> d, normalize.
// ---------------------------------------------------------------------------
__global__ __launch_bounds__(256) void attn_merge(const unsigned short* __restrict__ Opart,
                                                  const float* __restrict__ l_ws,
                                                  float* __restrict__ out) {
  int idx = blockIdx.x * 256 + threadIdx.x;   // S*8 threads
  int row = idx >> 3, m = idx & 7;
  int nc = (row >> 9) + 1;   // chunks with chunk_start <= row (CHUNK=512)

  float acc[8] = {0, 0, 0, 0, 0, 0, 0, 0};
  float L = 0.0f;
  for (int c = 0; c < nc; ++c) {
    L += l_ws[c * S_LEN + row];
    ushort8v o = *(const ushort8v*)(Opart + ((size_t)c * S_LEN + row) * DKD + m * 8);
#pragma unroll
    for (int j = 0; j < 8; ++j) acc[j] += bf2f(o[j]);
  }
  float inv = 1.0f / L;
  // sd = 8m + j ; d = 16*(j&3) + 2m + (j>>2)
#pragma unroll
  for (int j0 = 0; j0 < 4; ++j0) {
    float2 w2 = { acc[j0] * inv, acc[j0 + 4] * inv };
    *(float2*)(out + (size_t)row * DKD + 16 * j0 + 2 * m) = w2;
  }
}

// ---------------------------------------------------------------------------
// Fallback (ws too small): single-pass flash kernel, fp32 inputs.
// ---------------------------------------------------------------------------
__global__ __launch_bounds__(128) void attn_fwd(const float* __restrict__ qg,
                                                const float* __restrict__ kg,
                                                const float* __restrict__ vg,
                                                float* __restrict__ out) {
  __shared__ __align__(16) unsigned short Qs[32][LDK];
  __shared__ __align__(16) unsigned short Ksh[BN][LDK];
  __shared__ __align__(16) unsigned short Vt[DKD][LDK];
  __shared__ __align__(16) unsigned short Ps[2][16][LDK];

  const int tid = threadIdx.x, wave = tid >> 6, lane = tid & 63;
  const int col = lane & 15, quad = lane >> 4;
  const int q0 = blockIdx.x * 32;

#pragma unroll
  for (int r = 0; r < 4; ++r) {
    int vi = tid + r * 128;
    int row = vi >> 4, c4 = vi & 15;
    if (row < 32) {
      float4 val = *(const float4*)(qg + (size_t)(q0 + row) * DKD + c4 * 4);
      Qs[row][c4 * 4 + 0] = f2bf(val.x);
      Qs[row][c4 * 4 + 1] = f2bf(val.y);
      Qs[row][c4 * 4 + 2] = f2bf(val.z);
      Qs[row][c4 * 4 + 3] = f2bf(val.w);
    }
  }

  float m_run[4], l_run[4];
  f32x4 Of[4];
#pragma unroll
  for (int i = 0; i < 4; ++i) {
    m_run[i] = -1e30f; l_run[i] = 0.0f;
    Of[i] = f32x4{0.0f, 0.0f, 0.0f, 0.0f};
  }

  const int n_tiles = (q0 + 31) / BN + 1;
  for (int it = 0; it < n_tiles; ++it) {
    __syncthreads();
    const int k0 = it * BN;
#pragma unroll
    for (int r = 0; r < 8; ++r) {
      int vi = tid + r * 128;
      int row = vi >> 4, c4 = vi & 15;
      float4 kv = *(const float4*)(kg + (size_t)(k0 + row) * DKD + c4 * 4);
      Ksh[row][c4 * 4 + 0] = f2bf(kv.x);
      Ksh[row][c4 * 4 + 1] = f2bf(kv.y);
      Ksh[row][c4 * 4 + 2] = f2bf(kv.z);
      Ksh[row][c4 * 4 + 3] = f2bf(kv.w);
      float4 vv = *(const float4*)(vg + (size_t)(k0 + row) * DKD + c4 * 4);
      Vt[c4 * 4 + 0][row] = f2bf(vv.x);
      Vt[c4 * 4 + 1][row] = f2bf(vv.y);
      Vt[c4 * 4 + 2][row] = f2bf(vv.z);
      Vt[c4 * 4 + 3][row] = f2bf(vv.w);
    }
    __syncthreads();

    f32x4 Sf[4];
    const unsigned short* qrow = &Qs[wave * 16 + col][0];
#pragma unroll
    for (int t = 0; t < 4; ++t) {
      f32x4 acc = f32x4{0.0f, 0.0f, 0.0f, 0.0f};
#pragma unroll
      for (int c = 0; c < 2; ++c) {
        bf16x8 a = *(const bf16x8*)(qrow + c * 32 + quad * 8);
        bf16x8 b = *(const bf16x8*)(&Ksh[t * 16 + col][c * 32 + quad * 8]);
        acc = __builtin_amdgcn_mfma_f32_16x16x32_bf16(a, b, acc, 0, 0, 0);
      }
      Sf[t] = acc;
    }

    const float scale = 1.0f / 64.0f;
    float rmax[4] = {-1e30f, -1e30f, -1e30f, -1e30f};
#pragma unroll
    for (int t = 0; t < 4; ++t) {
      int kidx = k0 + t * 16 + col;
#pragma unroll
      for (int r = 0; r < 4; ++r) {
        int qidx = q0 + wave * 16 + quad * 4 + r;
        float s = Sf[t][r] * scale;
        s = (kidx <= qidx) ? s : -1e30f;
        Sf[t][r] = s;
        rmax[r] = fmaxf(rmax[r], s);
      }
    }
#pragma unroll
    for (int off = 1; off <= 8; off <<= 1)
#pragma unroll
      for (int r = 0; r < 4; ++r)
        rmax[r] = fmaxf(rmax[r], __shfl_xor(rmax[r], off));

    float alpha[4], rsum[4];
#pragma unroll
    for (int r = 0; r < 4; ++r) {
      float mn = fmaxf(m_run[r], rmax[r]);
      alpha[r] = __expf(m_run[r] - mn);
      m_run[r] = mn;
      rsum[r] = 0.0f;
    }
#pragma unroll
    for (int t = 0; t < 4; ++t)
#pragma unroll
      for (int r = 0; r < 4; ++r) {
        float p = __expf(Sf[t][r] - m_run[r]);
        Sf[t][r] = p;
        rsum[r] += p;
      }
#pragma unroll
    for (int off = 1; off <= 8; off <<= 1)
#pragma unroll
      for (int r = 0; r < 4; ++r)
        rsum[r] += __shfl_xor(rsum[r], off);
#pragma unroll
    for (int r = 0; r < 4; ++r)
      l_run[r] = l_run[r] * alpha[r] + rsum[r];
#pragma unroll
    for (int dt = 0; dt < 4; ++dt)
#pragma unroll
      for (int r = 0; r < 4; ++r)
        Of[dt][r] *= alpha[r];

#pragma unroll
    for (int t = 0; t < 4; ++t)
#pragma unroll
      for (int r = 0; r < 4; ++r)
        Ps[wave][quad * 4 + r][t * 16 + col] = f2bf(Sf[t][r]);
    __syncthreads();

    const unsigned short* prow = &Ps[wave][col][0];
#pragma unroll
    for (int dt = 0; dt < 4; ++dt) {
#pragma unroll
      for (int c = 0; c < 2; ++c) {
        bf16x8 a = *(const bf16x8*)(prow + c * 32 + quad * 8);
        bf16x8 b = *(const bf16x8*)(&Vt[dt * 16 + col][c * 32 + quad * 8]);
        Of[dt] = __builtin_amdgcn_mfma_f32_16x16x32_bf16(a, b, Of[dt], 0, 0, 0);
      }
    }
  }

#pragma unroll
  for (int r = 0; r < 4; ++r) {
    float inv = 1.0f / l_run[r];
    int qrow_g = q0 + wave * 16 + quad * 4 + r;
#pragma unroll
    for (int dt = 0; dt < 4; ++dt)
      out[(size_t)qrow_g * DKD + dt * 16 + col] = Of[dt][r] * inv;
  }
}

extern "C" void kernel_launch(void* const* d_in, const int* in_sizes, int n_in,
                              void* d_out, int out_size, void* d_ws, size_t ws_size,
                              hipStream_t stream) {
  const float* q = (const float*)d_in[0];
  const float* k = (const float*)d_in[1];
  const float* v = (const float*)d_in[2];
  float* out = (float*)d_out;

  if (ws_size >= WS_NEED) {
    unsigned short* Ff    = (unsigned short*)d_ws;
    float* l_ws           = (float*)(Ff + (size_t)2 * S_LEN * DKD);
    unsigned short* Opart = (unsigned short*)(l_ws + (size_t)NC * S_LEN);

    hipLaunchKernelGGL(precompute, dim3(S_LEN / 64), dim3(256), 0, stream, k, v, Ff);
    hipLaunchKernelGGL(attn_partial, dim3(NWORK), dim3(256), 0, stream,
                       q, Ff, Opart, l_ws);
    hipLaunchKernelGGL(attn_merge, dim3(S_LEN * 8 / 256), dim3(256), 0, stream,
                       Opart, l_ws, out);
  } else {
    hipLaunchKernelGGL(attn_fwd, dim3(S_LEN / 32), dim3(128), 0, stream, q, k, v, out);
  }
}